// Round 6
// baseline (99204.205 us; speedup 1.0000x reference)
//
#include <hip/hip_runtime.h>

// ---------------------------------------------------------------------------
// BasicModel_43387759624704: 2-layer GRU (T=512, B=256, H=512, COV=128),
// ragged masking, covariate head, exp(-dist) head. Inputs/outputs FLOAT32
// (verified round 5); MFMA operands bf16 in workspace, f32 accumulate/state.
//
// ROUND 6: persistent per-chunk GRU scan (Whh LDS-resident for all TC steps,
// per-row-group 32-block monotonic counter barrier, agent-scope coherent h
// exchange). Replaces the 1024 one-step launches of round 5 (launch-bound).
// ---------------------------------------------------------------------------

typedef unsigned short u16;
typedef unsigned long long u64;
typedef __attribute__((ext_vector_type(8))) short short8;
typedef short8 bf16x8;
typedef __attribute__((ext_vector_type(4))) float f32x4;

#define T_DIM 512
#define B_DIM 256
#define H_DIM 512
#define G3H   1536
#define BT    131072        // 256*512
#define XPK   192           // padded K for layer-0 input GEMM (129 -> 192)
#define PRED_ELEMS 16875264 // 256*511*129

__device__ __forceinline__ u16 f2bf(float f) {  // RNE
    union { float f; unsigned i; } v; v.f = f;
    unsigned i = v.i;
    return (u16)((i + 0x7FFFu + ((i >> 16) & 1u)) >> 16);
}
__device__ __forceinline__ float bf2f(u16 u) {
    union { unsigned i; float f; } v; v.i = ((unsigned)u) << 16; return v.f;
}
__device__ __forceinline__ float sigm(float x) { return 1.f / (1.f + __expf(-x)); }
__device__ __forceinline__ float tanh_f(float x) {
    float ax = fabsf(x);
    float e = __expf(-2.f * ax);
    float t = (1.f - e) / (1.f + e);
    return x < 0.f ? -t : t;
}
// coherent (device-scope) 16B load of bf16x8 via 2x relaxed agent atomics
__device__ __forceinline__ bf16x8 aload16(const u16* p) {
    union { bf16x8 v; u64 q[2]; } r;
    const u64* qp = (const u64*)p;
    r.q[0] = __hip_atomic_load(qp + 0, __ATOMIC_RELAXED, __HIP_MEMORY_SCOPE_AGENT);
    r.q[1] = __hip_atomic_load(qp + 1, __ATOMIC_RELAXED, __HIP_MEMORY_SCOPE_AGENT);
    return r.v;
}

// ---------------------------------------------------------------------------
__global__ void zero_ctr_kernel(unsigned* ctr) {
    for (int i = threadIdx.x; i < 2048; i += 256) ctr[i] = 0u;
}

// f32 [rows][srcK] -> bf16 [rows][dstK] (zero-pad cols >= srcK)
__global__ void cvt_pad_kernel(const float* __restrict__ src, u16* __restrict__ dst,
                               int rows, int srcK, int dstK) {
    int n = rows * dstK;
    for (int idx = blockIdx.x * blockDim.x + threadIdx.x; idx < n;
         idx += gridDim.x * blockDim.x) {
        int row = idx / dstK, col = idx - row * dstK;
        float v = (col < srcK) ? src[(size_t)row * srcK + col] : 0.f;
        dst[idx] = f2bf(v);
    }
}

// W_cov f32 [128][513] -> bf16 [128][512] + f32 wlast[128] (col 512)
__global__ void cvt_wcov_kernel(const float* __restrict__ Wcov,
                                u16* __restrict__ WcovBf, float* __restrict__ wlastf) {
    int idx0 = blockIdx.x * blockDim.x + threadIdx.x;
    for (int idx = idx0; idx < 128 * 512; idx += gridDim.x * blockDim.x) {
        int row = idx >> 9, col = idx & 511;
        WcovBf[idx] = f2bf(Wcov[row * 513 + col]);
    }
    if (idx0 < 128) wlastf[idx0] = Wcov[idx0 * 513 + 512];
}

// ---------------------------------------------------------------------------
// C[m][n] = sum_k A[m][k]*B[n][k] + bias[n]; A,B bf16 K-major; bias f32; C bf16
__global__ __launch_bounds__(256) void gemm_bias_kernel(
    const u16* __restrict__ A, int lda, const u16* __restrict__ B, int ldb,
    const float* __restrict__ bias, u16* __restrict__ C, int ldc, int K) {
    __shared__ __attribute__((aligned(16))) u16 Ash[128 * 72];
    __shared__ __attribute__((aligned(16))) u16 Bsh[128 * 72];
    const int tid = threadIdx.x, lane = tid & 63, w = tid >> 6;
    const int m0 = blockIdx.y * 128, n0 = blockIdx.x * 128;
    const int r0 = (w & 1) * 64, c0 = (w >> 1) * 64;
    const int am = lane & 15, aq = lane >> 4;
    f32x4 acc[4][4] = {};
    for (int kt = 0; kt < K; kt += 64) {
        __syncthreads();
#pragma unroll
        for (int s = 0; s < 4; ++s) {
            int cid = tid + s * 256, row = cid >> 3, q = cid & 7;
            *(short8*)&Ash[row * 72 + q * 8] =
                *(const short8*)(A + (size_t)(m0 + row) * lda + kt + q * 8);
            *(short8*)&Bsh[row * 72 + q * 8] =
                *(const short8*)(B + (size_t)(n0 + row) * ldb + kt + q * 8);
        }
        __syncthreads();
#pragma unroll
        for (int ks = 0; ks < 2; ++ks) {
            const int kof = ks * 32 + aq * 8;
            bf16x8 a[4], bb[4];
#pragma unroll
            for (int f = 0; f < 4; ++f)
                a[f] = *(short8*)&Ash[(r0 + f * 16 + am) * 72 + kof];
#pragma unroll
            for (int f = 0; f < 4; ++f)
                bb[f] = *(short8*)&Bsh[(c0 + f * 16 + am) * 72 + kof];
#pragma unroll
            for (int fi = 0; fi < 4; ++fi)
#pragma unroll
                for (int fj = 0; fj < 4; ++fj)
                    acc[fi][fj] = __builtin_amdgcn_mfma_f32_16x16x32_bf16(
                        a[fi], bb[fj], acc[fi][fj], 0, 0, 0);
        }
    }
#pragma unroll
    for (int fj = 0; fj < 4; ++fj) {
        const int col = n0 + c0 + fj * 16 + am;
        const float bia = bias[col];
#pragma unroll
        for (int fi = 0; fi < 4; ++fi) {
#pragma unroll
            for (int r = 0; r < 4; ++r) {
                const int row = m0 + r0 + fi * 16 + aq * 4 + r;
                C[(size_t)row * ldc + col] = f2bf(acc[fi][fj][r] + bia);
            }
        }
    }
}

// ---------------------------------------------------------------------------
// Persistent GRU scan over one time chunk. Grid (32 col-blocks, 16 row-groups)
// = 512 blocks = exactly 2/CU (LDS 62.4 KB, __launch_bounds__(256,2)).
// Block owns a 16-batch x 16-col patch of h; Whh slice (3 gates x 16 cols x
// 512 K) stays in LDS for all TC steps. Waves split K 4-way; partials reduced
// in LDS. Per-step sync: only the 32 col-blocks of a row group exchange data
// (they produce/consume the same 16 batch rows of h) -> per-row-group
// monotonic counter barrier; h published via agent-scope coherent stores.
__global__ __launch_bounds__(256, 2) void scan_gru_kernel(
    const u16* __restrict__ gi,      // [TC][256][1536] chunk (bf16)
    const u16* __restrict__ Whh,     // [1536][512] bf16
    const float* __restrict__ bhh,   // [1536] f32
    const int* __restrict__ lengths, // [256]
    const float* __restrict__ h0l,   // [256][512] f32 (layer slice)
    const u16* __restrict__ h0bfl,   // [256][512] bf16 (layer slice)
    u16* __restrict__ o,             // [TC][256][512] chunk (bf16)
    u16* __restrict__ hbf,           // [2][256][512] bf16 state (parity by t)
    float* __restrict__ hlast,       // [256][512] f32 carry (layer slice)
    unsigned* __restrict__ ctr,      // 16 counters, stride 64 uints
    int t0, int TC, unsigned base) {
    __shared__ __attribute__((aligned(16))) u16 Wl[48 * 520];
    __shared__ __attribute__((aligned(16))) float P[4 * 3 * 256];
    __shared__ __attribute__((aligned(16))) float bhhf[48];
    const int tid = threadIdx.x, lane = tid & 63, w = tid >> 6;
    const int n0 = blockIdx.x * 16, b0 = blockIdx.y * 16;
    // one-time: stage Whh slice into LDS (rows: 3 gates x 16 cols, K=512)
#pragma unroll
    for (int it = 0; it < 12; ++it) {
        int f = it * 2048 + tid * 8;
        int j = f >> 9, k = f & 511;
        *(short8*)&Wl[j * 520 + k] =
            *(const short8*)(Whh + ((size_t)((j >> 4) * 512 + n0 + (j & 15))) * 512 + k);
    }
    if (tid < 48) bhhf[tid] = bhh[(tid >> 4) * 512 + n0 + (tid & 15)];
    const int m = tid >> 4, c = tid & 15;
    const int b = b0 + m, col = n0 + c;
    float h = (t0 == 0) ? h0l[(size_t)b * 512 + col]
                        : hlast[(size_t)b * 512 + col];
    const int len = lengths[b];
    const int am = lane & 15, aq = lane >> 4;
    unsigned* myctr = ctr + blockIdx.y * 64;
    __syncthreads();
    for (int tl = 0; tl < TC; ++tl) {
        const int t = t0 + tl;
        const u16* Asrc = (t == 0) ? h0bfl : (hbf + (size_t)((t - 1) & 1) * BT);
        f32x4 ar = {}, az = {}, an = {};
#pragma unroll
        for (int kb = 0; kb < 4; ++kb) {
            const int k = w * 128 + kb * 32 + aq * 8;
            bf16x8 a = aload16(Asrc + (size_t)(b0 + am) * 512 + k);  // coherent
            bf16x8 wr = *(short8*)&Wl[(0 + am) * 520 + k];
            bf16x8 wz = *(short8*)&Wl[(16 + am) * 520 + k];
            bf16x8 wn = *(short8*)&Wl[(32 + am) * 520 + k];
            ar = __builtin_amdgcn_mfma_f32_16x16x32_bf16(a, wr, ar, 0, 0, 0);
            az = __builtin_amdgcn_mfma_f32_16x16x32_bf16(a, wz, az, 0, 0, 0);
            an = __builtin_amdgcn_mfma_f32_16x16x32_bf16(a, wn, an, 0, 0, 0);
        }
#pragma unroll
        for (int r = 0; r < 4; ++r) {
            P[(w * 3 + 0) * 256 + (aq * 4 + r) * 16 + am] = ar[r];
            P[(w * 3 + 1) * 256 + (aq * 4 + r) * 16 + am] = az[r];
            P[(w * 3 + 2) * 256 + (aq * 4 + r) * 16 + am] = an[r];
        }
        __syncthreads();
        float Cr = bhhf[c], Cz = bhhf[16 + c], Cn = bhhf[32 + c];
#pragma unroll
        for (int w2 = 0; w2 < 4; ++w2) {
            Cr += P[(w2 * 3 + 0) * 256 + tid];
            Cz += P[(w2 * 3 + 1) * 256 + tid];
            Cn += P[(w2 * 3 + 2) * 256 + tid];
        }
        const size_t gib = ((size_t)tl * 256 + b) * (size_t)G3H + n0 + c;
        float r_ = sigm(bf2f(gi[gib]) + Cr);
        float z_ = sigm(bf2f(gi[gib + 512]) + Cz);
        float n_ = tanh_f(bf2f(gi[gib + 1024]) + r_ * Cn);
        float hnew = (1.f - z_) * n_ + z_ * h;
        bool valid = t < len;
        h = valid ? hnew : h;
        o[((size_t)tl * 256 + b) * 512 + col] = f2bf(valid ? hnew : 0.f);
        // coherent publish of h for peer col-blocks of this row group
        __hip_atomic_store(hbf + (size_t)(t & 1) * BT + (size_t)b * 512 + col,
                           f2bf(h), __ATOMIC_RELAXED, __HIP_MEMORY_SCOPE_AGENT);
        if (tl < TC - 1) {
            __threadfence();
            __syncthreads();
            if (tid == 0) {
                __hip_atomic_fetch_add(myctr, 1u, __ATOMIC_RELEASE,
                                       __HIP_MEMORY_SCOPE_AGENT);
                const unsigned tgt = base + (unsigned)(tl + 1) * 32u;
                while (__hip_atomic_load(myctr, __ATOMIC_ACQUIRE,
                                         __HIP_MEMORY_SCOPE_AGENT) < tgt)
                    __builtin_amdgcn_s_sleep(1);
            }
            __syncthreads();
            __threadfence();
        } else {
            hlast[(size_t)b * 512 + col] = h;  // f32 carry across chunks / final
        }
    }
}

// ---------------------------------------------------------------------------
// preds[b][t][c] = mask * (o1[t,b,:]@WcovBf[c,:] + x[t,b,0]*wlast[c] + bcov[c])
__global__ __launch_bounds__(256) void preds_kernel(
    const u16* __restrict__ o1c, const u16* __restrict__ WcovBf,
    const float* __restrict__ wlastf, const float* __restrict__ bcov,
    const float* __restrict__ x, const int* __restrict__ lengths,
    float* __restrict__ out, int t0, int TC) {
    __shared__ __attribute__((aligned(16))) u16 Ash[64 * 72];
    __shared__ __attribute__((aligned(16))) u16 Bsh[128 * 72];
    const int tid = threadIdx.x, lane = tid & 63, w = tid >> 6;
    const int tb0 = blockIdx.x * 64, b = blockIdx.y;
    const int am = lane & 15, aq = lane >> 4;
    f32x4 acc[8] = {};
    for (int kt = 0; kt < 512; kt += 64) {
        __syncthreads();
#pragma unroll
        for (int s = 0; s < 2; ++s) {
            int cid = tid + s * 256, row = cid >> 3, q = cid & 7;
            int tl = tb0 + row;
            short8 v = {};
            if (tl < TC && (t0 + tl) < 511)
                v = *(const short8*)(o1c + ((size_t)tl * 256 + b) * 512 + kt + q * 8);
            *(short8*)&Ash[row * 72 + q * 8] = v;
        }
#pragma unroll
        for (int s = 0; s < 4; ++s) {
            int cid = tid + s * 256, row = cid >> 3, q = cid & 7;
            *(short8*)&Bsh[row * 72 + q * 8] =
                *(const short8*)(WcovBf + (size_t)row * 512 + kt + q * 8);
        }
        __syncthreads();
#pragma unroll
        for (int ks = 0; ks < 2; ++ks) {
            const int kof = ks * 32 + aq * 8;
            bf16x8 a = *(short8*)&Ash[(w * 16 + am) * 72 + kof];
#pragma unroll
            for (int fj = 0; fj < 8; ++fj) {
                bf16x8 bb = *(short8*)&Bsh[(fj * 16 + am) * 72 + kof];
                acc[fj] = __builtin_amdgcn_mfma_f32_16x16x32_bf16(a, bb, acc[fj], 0, 0, 0);
            }
        }
    }
    const int len = lengths[b];
#pragma unroll
    for (int r = 0; r < 4; ++r) {
        const int tl = tb0 + w * 16 + aq * 4 + r;
        const int t = t0 + tl;
        if (tl >= TC || t >= 511) continue;
        const float tim = x[(size_t)t * (256 * 129) + b * 129];
        const bool valid = t < (len - 1);
        const size_t ob = (size_t)b * (511 * 129) + (size_t)t * 129;
#pragma unroll
        for (int fj = 0; fj < 8; ++fj) {
            const int cc = fj * 16 + am;
            float v = acc[fj][r] + bcov[cc] + tim * wlastf[cc];
            out[ob + cc] = valid ? v : 0.f;
        }
    }
    if (tid < 64) {  // channel 128 is always zero
        int tl = tb0 + tid, t = t0 + tl;
        if (tl < TC && t < 511)
            out[(size_t)b * (511 * 129) + (size_t)t * 129 + 128] = 0.f;
    }
}

// ---------------------------------------------------------------------------
// dist[i][p] = exp(-(last_flat[i] @ W_par[p] + b_par[p])), f32 out.
__global__ void dist_kernel(const float* __restrict__ hl0,
                            const float* __restrict__ hl1,
                            const float* __restrict__ Wpar,
                            const float* __restrict__ bpar, float* __restrict__ out) {
    const int w = threadIdx.x >> 6, lane = threadIdx.x & 63;
    const float bp0 = bpar[0], bp1 = bpar[1];
    for (int rr = 0; rr < 8; ++rr) {
        const int i = (blockIdx.x * 4 + w) * 8 + rr;
        const int l = i >> 7, bb = (2 * i) & 255;
        const float* base = (l ? hl1 : hl0) + (size_t)bb * 512;
        float a0 = 0.f, a1 = 0.f;
#pragma unroll
        for (int cc = 0; cc < 16; ++cc) {
            const int k = cc * 64 + lane;
            const float v = base[k];
            a0 += v * Wpar[k];
            a1 += v * Wpar[1024 + k];
        }
#pragma unroll
        for (int off = 32; off; off >>= 1) {
            a0 += __shfl_down(a0, off);
            a1 += __shfl_down(a1, off);
        }
        if (lane == 0) {
            out[PRED_ELEMS + i * 2 + 0] = __expf(-(a0 + bp0));
            out[PRED_ELEMS + i * 2 + 1] = __expf(-(a1 + bp1));
        }
    }
}

// ---------------------------------------------------------------------------
extern "C" void kernel_launch(void* const* d_in, const int* in_sizes, int n_in,
                              void* d_out, int out_size, void* d_ws, size_t ws_size,
                              hipStream_t stream) {
    const float* x    = (const float*)d_in[0];
    const int* lens   = (const int*)d_in[1];
    const float* h0   = (const float*)d_in[2];
    const float* Wih0 = (const float*)d_in[3];
    const float* Whh0 = (const float*)d_in[4];
    const float* bih0 = (const float*)d_in[5];
    const float* bhh0 = (const float*)d_in[6];
    const float* Wih1 = (const float*)d_in[7];
    const float* Whh1 = (const float*)d_in[8];
    const float* bih1 = (const float*)d_in[9];
    const float* bhh1 = (const float*)d_in[10];
    const float* Wcov = (const float*)d_in[11];
    const float* bcov = (const float*)d_in[12];
    const float* Wpar = (const float*)d_in[13];
    const float* bpar = (const float*)d_in[14];
    float* out = (float*)d_out;
    char* wsb = (char*)d_ws;

    size_t off = 0;
    auto take = [&](size_t bytes) -> size_t {
        size_t r = off; off += (bytes + 255) & ~(size_t)255; return r;
    };
    const size_t oCtr   = take(8192);                   // 2 layers x 16 ctrs
    const size_t oHl0   = take((size_t)BT * 4);         // layer0 f32 carry
    const size_t oHl1   = take((size_t)BT * 4);         // layer1 f32 carry
    const size_t oHbf0  = take((size_t)2 * BT * 2);     // layer0 bf16 parity
    const size_t oHbf1  = take((size_t)2 * BT * 2);     // layer1 bf16 parity
    const size_t oH0bf  = take((size_t)2 * BT * 2);     // bf16(h0) both layers
    const size_t oWih0b = take((size_t)G3H * XPK * 2);
    const size_t oWih1b = take((size_t)G3H * 512 * 2);
    const size_t oWhh0b = take((size_t)G3H * 512 * 2);
    const size_t oWhh1b = take((size_t)G3H * 512 * 2);
    const size_t oWcovb = take((size_t)128 * 512 * 2);
    const size_t oWlast = take(512);
    const size_t fixed = off;

    const size_t per = (size_t)256 * XPK * 2 + (size_t)256 * G3H * 2 +
                       2 * (size_t)256 * 512 * 2 + 2048;
    const size_t remain = ws_size > fixed ? ws_size - fixed : 0;
    int TC = 1;
    const int cands[10] = {512, 256, 128, 64, 32, 16, 8, 4, 2, 1};
    for (int i = 0; i < 10; ++i)
        if ((size_t)cands[i] * per <= remain) { TC = cands[i]; break; }

    const size_t oXbf = take((size_t)TC * 256 * XPK * 2);
    const size_t oGi  = take((size_t)TC * 256 * G3H * 2);
    const size_t oO0  = take((size_t)TC * 256 * 512 * 2);
    const size_t oO1  = take((size_t)TC * 256 * 512 * 2);

    unsigned* ctr = (unsigned*)(wsb + oCtr);
    float* hl0  = (float*)(wsb + oHl0);
    float* hl1  = (float*)(wsb + oHl1);
    u16* hbf0   = (u16*)(wsb + oHbf0);
    u16* hbf1   = (u16*)(wsb + oHbf1);
    u16* h0bf   = (u16*)(wsb + oH0bf);
    u16* wih0b  = (u16*)(wsb + oWih0b);
    u16* wih1b  = (u16*)(wsb + oWih1b);
    u16* whh0b  = (u16*)(wsb + oWhh0b);
    u16* whh1b  = (u16*)(wsb + oWhh1b);
    u16* wcovb  = (u16*)(wsb + oWcovb);
    float* wlastf = (float*)(wsb + oWlast);
    u16* xbfc   = (u16*)(wsb + oXbf);
    u16* gic    = (u16*)(wsb + oGi);
    u16* o0c    = (u16*)(wsb + oO0);
    u16* o1c    = (u16*)(wsb + oO1);

    zero_ctr_kernel<<<1, 256, 0, stream>>>(ctr);
    cvt_pad_kernel<<<288, 256, 0, stream>>>(Wih0, wih0b, G3H, 129, XPK);
    cvt_pad_kernel<<<768, 256, 0, stream>>>(Wih1, wih1b, G3H, 512, 512);
    cvt_pad_kernel<<<768, 256, 0, stream>>>(Whh0, whh0b, G3H, 512, 512);
    cvt_pad_kernel<<<768, 256, 0, stream>>>(Whh1, whh1b, G3H, 512, 512);
    cvt_pad_kernel<<<256, 256, 0, stream>>>(h0, h0bf, 512, 512, 512);
    cvt_wcov_kernel<<<64, 256, 0, stream>>>(Wcov, wcovb, wlastf);

    unsigned base = 0;
    for (int t0 = 0; t0 < T_DIM; t0 += TC) {
        int n = TC * 256 * XPK;
        int pg = (n + 255) / 256; if (pg > 2048) pg = 2048;
        cvt_pad_kernel<<<pg, 256, 0, stream>>>(
            x + (size_t)t0 * 256 * 129, xbfc, TC * 256, 129, XPK);
        gemm_bias_kernel<<<dim3(12, TC * 2), 256, 0, stream>>>(
            xbfc, XPK, wih0b, XPK, bih0, gic, G3H, XPK);
        scan_gru_kernel<<<dim3(32, 16), 256, 0, stream>>>(
            gic, whh0b, bhh0, lens, h0, h0bf, o0c, hbf0, hl0,
            ctr, t0, TC, base);
        gemm_bias_kernel<<<dim3(12, TC * 2), 256, 0, stream>>>(
            o0c, H_DIM, wih1b, H_DIM, bih1, gic, G3H, H_DIM);
        scan_gru_kernel<<<dim3(32, 16), 256, 0, stream>>>(
            gic, whh1b, bhh1, lens, h0 + (size_t)BT, h0bf + (size_t)BT,
            o1c, hbf1, hl1, ctr + 1024, t0, TC, base);
        preds_kernel<<<dim3((TC + 63) / 64, 256), 256, 0, stream>>>(
            o1c, wcovb, wlastf, bcov, x, lens, out, t0, TC);
        base += (unsigned)(TC - 1) * 32u;
    }
    dist_kernel<<<8, 256, 0, stream>>>(hl0, hl1, Wpar, bpar, out);
}

// Round 7
// 5751.612 us; speedup vs baseline: 17.2481x; 17.2481x over previous
//
#include <hip/hip_runtime.h>

// ---------------------------------------------------------------------------
// BasicModel_43387759624704: 2-layer GRU (T=512, B=256, H=512, COV=128),
// ragged masking, covariate head, exp(-dist) head. Inputs/outputs FLOAT32;
// MFMA operands bf16 in workspace, f32 accumulate/state.
//
// ROUND 7: persistent per-chunk scan with a FENCE-FREE barrier protocol.
// Round 6's __threadfence/ACQUIRE barrier cost ~94 us/step (buffer_wbl2 L2
// writebacks serializing per-XCD). All cross-block traffic now uses RELAXED
// agent-scope atomics (sc0/sc1: write-through stores, cache-bypassing loads
// -> MALL coherence point), ordered by a raw `s_waitcnt vmcnt(0)` between the
// h publish and the counter add. Zero cache-maintenance instructions.
// ---------------------------------------------------------------------------

typedef unsigned short u16;
typedef unsigned long long u64;
typedef __attribute__((ext_vector_type(8))) short short8;
typedef short8 bf16x8;
typedef __attribute__((ext_vector_type(4))) float f32x4;

#define T_DIM 512
#define B_DIM 256
#define H_DIM 512
#define G3H   1536
#define BT    131072        // 256*512
#define XPK   192           // padded K for layer-0 input GEMM (129 -> 192)
#define PRED_ELEMS 16875264 // 256*511*129

__device__ __forceinline__ u16 f2bf(float f) {  // RNE
    union { float f; unsigned i; } v; v.f = f;
    unsigned i = v.i;
    return (u16)((i + 0x7FFFu + ((i >> 16) & 1u)) >> 16);
}
__device__ __forceinline__ float bf2f(u16 u) {
    union { unsigned i; float f; } v; v.i = ((unsigned)u) << 16; return v.f;
}
__device__ __forceinline__ float sigm(float x) { return 1.f / (1.f + __expf(-x)); }
__device__ __forceinline__ float tanh_f(float x) {
    float ax = fabsf(x);
    float e = __expf(-2.f * ax);
    float t = (1.f - e) / (1.f + e);
    return x < 0.f ? -t : t;
}
// coherent 16B load (2x relaxed agent atomics: global_load sc0 sc1, no inv)
__device__ __forceinline__ bf16x8 aload16(const u16* p) {
    union { bf16x8 v; u64 q[2]; } r;
    const u64* qp = (const u64*)p;
    r.q[0] = __hip_atomic_load(qp + 0, __ATOMIC_RELAXED, __HIP_MEMORY_SCOPE_AGENT);
    r.q[1] = __hip_atomic_load(qp + 1, __ATOMIC_RELAXED, __HIP_MEMORY_SCOPE_AGENT);
    return r.v;
}

// ---------------------------------------------------------------------------
__global__ void zero_ctr_kernel(unsigned* ctr) {
    for (int i = threadIdx.x; i < 2048; i += 256) ctr[i] = 0u;
}

// f32 [rows][srcK] -> bf16 [rows][dstK] (zero-pad cols >= srcK)
__global__ void cvt_pad_kernel(const float* __restrict__ src, u16* __restrict__ dst,
                               int rows, int srcK, int dstK) {
    int n = rows * dstK;
    for (int idx = blockIdx.x * blockDim.x + threadIdx.x; idx < n;
         idx += gridDim.x * blockDim.x) {
        int row = idx / dstK, col = idx - row * dstK;
        float v = (col < srcK) ? src[(size_t)row * srcK + col] : 0.f;
        dst[idx] = f2bf(v);
    }
}

// W_cov f32 [128][513] -> bf16 [128][512] + f32 wlast[128] (col 512)
__global__ void cvt_wcov_kernel(const float* __restrict__ Wcov,
                                u16* __restrict__ WcovBf, float* __restrict__ wlastf) {
    int idx0 = blockIdx.x * blockDim.x + threadIdx.x;
    for (int idx = idx0; idx < 128 * 512; idx += gridDim.x * blockDim.x) {
        int row = idx >> 9, col = idx & 511;
        WcovBf[idx] = f2bf(Wcov[row * 513 + col]);
    }
    if (idx0 < 128) wlastf[idx0] = Wcov[idx0 * 513 + 512];
}

// ---------------------------------------------------------------------------
// C[m][n] = sum_k A[m][k]*B[n][k] + bias[n]; A,B bf16 K-major; bias f32; C bf16
__global__ __launch_bounds__(256) void gemm_bias_kernel(
    const u16* __restrict__ A, int lda, const u16* __restrict__ B, int ldb,
    const float* __restrict__ bias, u16* __restrict__ C, int ldc, int K) {
    __shared__ __attribute__((aligned(16))) u16 Ash[128 * 72];
    __shared__ __attribute__((aligned(16))) u16 Bsh[128 * 72];
    const int tid = threadIdx.x, lane = tid & 63, w = tid >> 6;
    const int m0 = blockIdx.y * 128, n0 = blockIdx.x * 128;
    const int r0 = (w & 1) * 64, c0 = (w >> 1) * 64;
    const int am = lane & 15, aq = lane >> 4;
    f32x4 acc[4][4] = {};
    for (int kt = 0; kt < K; kt += 64) {
        __syncthreads();
#pragma unroll
        for (int s = 0; s < 4; ++s) {
            int cid = tid + s * 256, row = cid >> 3, q = cid & 7;
            *(short8*)&Ash[row * 72 + q * 8] =
                *(const short8*)(A + (size_t)(m0 + row) * lda + kt + q * 8);
            *(short8*)&Bsh[row * 72 + q * 8] =
                *(const short8*)(B + (size_t)(n0 + row) * ldb + kt + q * 8);
        }
        __syncthreads();
#pragma unroll
        for (int ks = 0; ks < 2; ++ks) {
            const int kof = ks * 32 + aq * 8;
            bf16x8 a[4], bb[4];
#pragma unroll
            for (int f = 0; f < 4; ++f)
                a[f] = *(short8*)&Ash[(r0 + f * 16 + am) * 72 + kof];
#pragma unroll
            for (int f = 0; f < 4; ++f)
                bb[f] = *(short8*)&Bsh[(c0 + f * 16 + am) * 72 + kof];
#pragma unroll
            for (int fi = 0; fi < 4; ++fi)
#pragma unroll
                for (int fj = 0; fj < 4; ++fj)
                    acc[fi][fj] = __builtin_amdgcn_mfma_f32_16x16x32_bf16(
                        a[fi], bb[fj], acc[fi][fj], 0, 0, 0);
        }
    }
#pragma unroll
    for (int fj = 0; fj < 4; ++fj) {
        const int col = n0 + c0 + fj * 16 + am;
        const float bia = bias[col];
#pragma unroll
        for (int fi = 0; fi < 4; ++fi) {
#pragma unroll
            for (int r = 0; r < 4; ++r) {
                const int row = m0 + r0 + fi * 16 + aq * 4 + r;
                C[(size_t)row * ldc + col] = f2bf(acc[fi][fj][r] + bia);
            }
        }
    }
}

// ---------------------------------------------------------------------------
// Persistent GRU scan over one time chunk. Grid (32 col-blocks, 16 row-groups)
// = 512 blocks = exactly 2/CU. Whh slice LDS-resident for all TC steps.
// Fence-free barrier: wave 0 publishes the block's 16x16 h patch as 64 u64
// RELAXED agent atomics (write-through to MALL), drains with raw
// s_waitcnt vmcnt(0), then lane 0 RELAXED-adds the row-group counter and
// spins RELAXED. No buffer_wbl2 / buffer_inv anywhere in the loop.
__global__ __launch_bounds__(256, 2) void scan_gru_kernel(
    const u16* __restrict__ gi,      // [TC][256][1536] chunk (bf16)
    const u16* __restrict__ Whh,     // [1536][512] bf16
    const float* __restrict__ bhh,   // [1536] f32
    const int* __restrict__ lengths, // [256]
    const float* __restrict__ h0l,   // [256][512] f32 (layer slice)
    const u16* __restrict__ h0bfl,   // [256][512] bf16 (layer slice)
    u16* __restrict__ o,             // [TC][256][512] chunk (bf16)
    u16* __restrict__ hbf,           // [2][256][512] bf16 state (parity by t)
    float* __restrict__ hlast,       // [256][512] f32 carry (layer slice)
    unsigned* __restrict__ ctr,      // 16 counters, stride 64 uints
    int t0, int TC, unsigned base) {
    __shared__ __attribute__((aligned(16))) u16 Wl[48 * 520];
    __shared__ __attribute__((aligned(16))) float P[4 * 3 * 256];
    __shared__ __attribute__((aligned(16))) float bhhf[48];
    __shared__ __attribute__((aligned(8)))  u16 hX[256];
    const int tid = threadIdx.x, lane = tid & 63, w = tid >> 6;
    const int n0 = blockIdx.x * 16, b0 = blockIdx.y * 16;
    // one-time: stage Whh slice into LDS (rows: 3 gates x 16 cols, K=512)
#pragma unroll
    for (int it = 0; it < 12; ++it) {
        int f = it * 2048 + tid * 8;
        int j = f >> 9, k = f & 511;
        *(short8*)&Wl[j * 520 + k] =
            *(const short8*)(Whh + ((size_t)((j >> 4) * 512 + n0 + (j & 15))) * 512 + k);
    }
    if (tid < 48) bhhf[tid] = bhh[(tid >> 4) * 512 + n0 + (tid & 15)];
    const int m = tid >> 4, c = tid & 15;
    const int b = b0 + m, col = n0 + c;
    float h = (t0 == 0) ? h0l[(size_t)b * 512 + col]
                        : hlast[(size_t)b * 512 + col];
    const int len = lengths[b];
    const int am = lane & 15, aq = lane >> 4;
    unsigned* myctr = ctr + blockIdx.y * 64;
    // preload step-0 gi into registers
    size_t gib = (size_t)b * (size_t)G3H + n0 + c;
    float gr = bf2f(gi[gib]), gz = bf2f(gi[gib + 512]), gn = bf2f(gi[gib + 1024]);
    __syncthreads();
    for (int tl = 0; tl < TC; ++tl) {
        const int t = t0 + tl;
        const u16* Asrc = (t == 0) ? h0bfl : (hbf + (size_t)((t - 1) & 1) * BT);
        f32x4 ar = {}, az = {}, an = {};
#pragma unroll
        for (int kb = 0; kb < 4; ++kb) {
            const int k = w * 128 + kb * 32 + aq * 8;
            bf16x8 a = aload16(Asrc + (size_t)(b0 + am) * 512 + k);  // MALL-fresh
            bf16x8 wr = *(short8*)&Wl[(0 + am) * 520 + k];
            bf16x8 wz = *(short8*)&Wl[(16 + am) * 520 + k];
            bf16x8 wn = *(short8*)&Wl[(32 + am) * 520 + k];
            ar = __builtin_amdgcn_mfma_f32_16x16x32_bf16(a, wr, ar, 0, 0, 0);
            az = __builtin_amdgcn_mfma_f32_16x16x32_bf16(a, wz, az, 0, 0, 0);
            an = __builtin_amdgcn_mfma_f32_16x16x32_bf16(a, wn, an, 0, 0, 0);
        }
#pragma unroll
        for (int r = 0; r < 4; ++r) {
            P[(w * 3 + 0) * 256 + (aq * 4 + r) * 16 + am] = ar[r];
            P[(w * 3 + 1) * 256 + (aq * 4 + r) * 16 + am] = az[r];
            P[(w * 3 + 2) * 256 + (aq * 4 + r) * 16 + am] = an[r];
        }
        __syncthreads();
        float Cr = bhhf[c], Cz = bhhf[16 + c], Cn = bhhf[32 + c];
#pragma unroll
        for (int w2 = 0; w2 < 4; ++w2) {
            Cr += P[(w2 * 3 + 0) * 256 + tid];
            Cz += P[(w2 * 3 + 1) * 256 + tid];
            Cn += P[(w2 * 3 + 2) * 256 + tid];
        }
        float r_ = sigm(gr + Cr);
        float z_ = sigm(gz + Cz);
        float n_ = tanh_f(gn + r_ * Cn);
        float hnew = (1.f - z_) * n_ + z_ * h;
        bool valid = t < len;
        h = valid ? hnew : h;
        o[((size_t)tl * 256 + b) * 512 + col] = f2bf(valid ? hnew : 0.f);
        if (tl < TC - 1) {
            hX[tid] = f2bf(h);  // stage patch for wide publish
            // prefetch next step's gi (independent of the barrier)
            const size_t gib2 = ((size_t)(tl + 1) * 256 + b) * (size_t)G3H + n0 + c;
            gr = bf2f(gi[gib2]); gz = bf2f(gi[gib2 + 512]); gn = bf2f(gi[gib2 + 1024]);
            __syncthreads();  // hX ready; P consumed
            if (w == 0) {
                const int row = lane >> 2, cg = (lane & 3) * 4;
                union { u64 q; u16 s[4]; } pk;
                pk.s[0] = hX[row * 16 + cg + 0];
                pk.s[1] = hX[row * 16 + cg + 1];
                pk.s[2] = hX[row * 16 + cg + 2];
                pk.s[3] = hX[row * 16 + cg + 3];
                __hip_atomic_store(
                    (u64*)(hbf + (size_t)(t & 1) * BT + (size_t)(b0 + row) * 512 + n0 + cg),
                    pk.q, __ATOMIC_RELAXED, __HIP_MEMORY_SCOPE_AGENT);
                // order h stores before the counter add (wave-local drain; no cache ops)
                asm volatile("s_waitcnt vmcnt(0)" ::: "memory");
                if (lane == 0) {
                    __hip_atomic_fetch_add(myctr, 1u, __ATOMIC_RELAXED,
                                           __HIP_MEMORY_SCOPE_AGENT);
                    const unsigned tgt = base + (unsigned)(tl + 1) * 32u;
                    while (__hip_atomic_load(myctr, __ATOMIC_RELAXED,
                                             __HIP_MEMORY_SCOPE_AGENT) < tgt)
                        __builtin_amdgcn_s_sleep(2);
                }
            }
            __syncthreads();
        } else {
            // chunk's last step: next consumer is the next kernel launch
            // (stream order + end-of-kernel writeback) -> plain stores suffice
            hbf[(size_t)(t & 1) * BT + (size_t)b * 512 + col] = f2bf(h);
            hlast[(size_t)b * 512 + col] = h;
        }
    }
}

// ---------------------------------------------------------------------------
// preds[b][t][c] = mask * (o1[t,b,:]@WcovBf[c,:] + x[t,b,0]*wlast[c] + bcov[c])
__global__ __launch_bounds__(256) void preds_kernel(
    const u16* __restrict__ o1c, const u16* __restrict__ WcovBf,
    const float* __restrict__ wlastf, const float* __restrict__ bcov,
    const float* __restrict__ x, const int* __restrict__ lengths,
    float* __restrict__ out, int t0, int TC) {
    __shared__ __attribute__((aligned(16))) u16 Ash[64 * 72];
    __shared__ __attribute__((aligned(16))) u16 Bsh[128 * 72];
    const int tid = threadIdx.x, lane = tid & 63, w = tid >> 6;
    const int tb0 = blockIdx.x * 64, b = blockIdx.y;
    const int am = lane & 15, aq = lane >> 4;
    f32x4 acc[8] = {};
    for (int kt = 0; kt < 512; kt += 64) {
        __syncthreads();
#pragma unroll
        for (int s = 0; s < 2; ++s) {
            int cid = tid + s * 256, row = cid >> 3, q = cid & 7;
            int tl = tb0 + row;
            short8 v = {};
            if (tl < TC && (t0 + tl) < 511)
                v = *(const short8*)(o1c + ((size_t)tl * 256 + b) * 512 + kt + q * 8);
            *(short8*)&Ash[row * 72 + q * 8] = v;
        }
#pragma unroll
        for (int s = 0; s < 4; ++s) {
            int cid = tid + s * 256, row = cid >> 3, q = cid & 7;
            *(short8*)&Bsh[row * 72 + q * 8] =
                *(const short8*)(WcovBf + (size_t)row * 512 + kt + q * 8);
        }
        __syncthreads();
#pragma unroll
        for (int ks = 0; ks < 2; ++ks) {
            const int kof = ks * 32 + aq * 8;
            bf16x8 a = *(short8*)&Ash[(w * 16 + am) * 72 + kof];
#pragma unroll
            for (int fj = 0; fj < 8; ++fj) {
                bf16x8 bb = *(short8*)&Bsh[(fj * 16 + am) * 72 + kof];
                acc[fj] = __builtin_amdgcn_mfma_f32_16x16x32_bf16(a, bb, acc[fj], 0, 0, 0);
            }
        }
    }
    const int len = lengths[b];
#pragma unroll
    for (int r = 0; r < 4; ++r) {
        const int tl = tb0 + w * 16 + aq * 4 + r;
        const int t = t0 + tl;
        if (tl >= TC || t >= 511) continue;
        const float tim = x[(size_t)t * (256 * 129) + b * 129];
        const bool valid = t < (len - 1);
        const size_t ob = (size_t)b * (511 * 129) + (size_t)t * 129;
#pragma unroll
        for (int fj = 0; fj < 8; ++fj) {
            const int cc = fj * 16 + am;
            float v = acc[fj][r] + bcov[cc] + tim * wlastf[cc];
            out[ob + cc] = valid ? v : 0.f;
        }
    }
    if (tid < 64) {  // channel 128 is always zero
        int tl = tb0 + tid, t = t0 + tl;
        if (tl < TC && t < 511)
            out[(size_t)b * (511 * 129) + (size_t)t * 129 + 128] = 0.f;
    }
}

// ---------------------------------------------------------------------------
// dist[i][p] = exp(-(last_flat[i] @ W_par[p] + b_par[p])), f32 out.
__global__ void dist_kernel(const float* __restrict__ hl0,
                            const float* __restrict__ hl1,
                            const float* __restrict__ Wpar,
                            const float* __restrict__ bpar, float* __restrict__ out) {
    const int w = threadIdx.x >> 6, lane = threadIdx.x & 63;
    const float bp0 = bpar[0], bp1 = bpar[1];
    for (int rr = 0; rr < 8; ++rr) {
        const int i = (blockIdx.x * 4 + w) * 8 + rr;
        const int l = i >> 7, bb = (2 * i) & 255;
        const float* base = (l ? hl1 : hl0) + (size_t)bb * 512;
        float a0 = 0.f, a1 = 0.f;
#pragma unroll
        for (int cc = 0; cc < 16; ++cc) {
            const int k = cc * 64 + lane;
            const float v = base[k];
            a0 += v * Wpar[k];
            a1 += v * Wpar[1024 + k];
        }
#pragma unroll
        for (int off = 32; off; off >>= 1) {
            a0 += __shfl_down(a0, off);
            a1 += __shfl_down(a1, off);
        }
        if (lane == 0) {
            out[PRED_ELEMS + i * 2 + 0] = __expf(-(a0 + bp0));
            out[PRED_ELEMS + i * 2 + 1] = __expf(-(a1 + bp1));
        }
    }
}

// ---------------------------------------------------------------------------
extern "C" void kernel_launch(void* const* d_in, const int* in_sizes, int n_in,
                              void* d_out, int out_size, void* d_ws, size_t ws_size,
                              hipStream_t stream) {
    const float* x    = (const float*)d_in[0];
    const int* lens   = (const int*)d_in[1];
    const float* h0   = (const float*)d_in[2];
    const float* Wih0 = (const float*)d_in[3];
    const float* Whh0 = (const float*)d_in[4];
    const float* bih0 = (const float*)d_in[5];
    const float* bhh0 = (const float*)d_in[6];
    const float* Wih1 = (const float*)d_in[7];
    const float* Whh1 = (const float*)d_in[8];
    const float* bih1 = (const float*)d_in[9];
    const float* bhh1 = (const float*)d_in[10];
    const float* Wcov = (const float*)d_in[11];
    const float* bcov = (const float*)d_in[12];
    const float* Wpar = (const float*)d_in[13];
    const float* bpar = (const float*)d_in[14];
    float* out = (float*)d_out;
    char* wsb = (char*)d_ws;

    size_t off = 0;
    auto take = [&](size_t bytes) -> size_t {
        size_t r = off; off += (bytes + 255) & ~(size_t)255; return r;
    };
    const size_t oCtr   = take(8192);                   // 2 layers x 16 ctrs
    const size_t oHl0   = take((size_t)BT * 4);         // layer0 f32 carry
    const size_t oHl1   = take((size_t)BT * 4);         // layer1 f32 carry
    const size_t oHbf0  = take((size_t)2 * BT * 2);     // layer0 bf16 parity
    const size_t oHbf1  = take((size_t)2 * BT * 2);     // layer1 bf16 parity
    const size_t oH0bf  = take((size_t)2 * BT * 2);     // bf16(h0) both layers
    const size_t oWih0b = take((size_t)G3H * XPK * 2);
    const size_t oWih1b = take((size_t)G3H * 512 * 2);
    const size_t oWhh0b = take((size_t)G3H * 512 * 2);
    const size_t oWhh1b = take((size_t)G3H * 512 * 2);
    const size_t oWcovb = take((size_t)128 * 512 * 2);
    const size_t oWlast = take(512);
    const size_t fixed = off;

    const size_t per = (size_t)256 * XPK * 2 + (size_t)256 * G3H * 2 +
                       2 * (size_t)256 * 512 * 2 + 2048;
    const size_t remain = ws_size > fixed ? ws_size - fixed : 0;
    int TC = 1;
    const int cands[10] = {512, 256, 128, 64, 32, 16, 8, 4, 2, 1};
    for (int i = 0; i < 10; ++i)
        if ((size_t)cands[i] * per <= remain) { TC = cands[i]; break; }

    const size_t oXbf = take((size_t)TC * 256 * XPK * 2);
    const size_t oGi  = take((size_t)TC * 256 * G3H * 2);
    const size_t oO0  = take((size_t)TC * 256 * 512 * 2);
    const size_t oO1  = take((size_t)TC * 256 * 512 * 2);

    unsigned* ctr = (unsigned*)(wsb + oCtr);
    float* hl0  = (float*)(wsb + oHl0);
    float* hl1  = (float*)(wsb + oHl1);
    u16* hbf0   = (u16*)(wsb + oHbf0);
    u16* hbf1   = (u16*)(wsb + oHbf1);
    u16* h0bf   = (u16*)(wsb + oH0bf);
    u16* wih0b  = (u16*)(wsb + oWih0b);
    u16* wih1b  = (u16*)(wsb + oWih1b);
    u16* whh0b  = (u16*)(wsb + oWhh0b);
    u16* whh1b  = (u16*)(wsb + oWhh1b);
    u16* wcovb  = (u16*)(wsb + oWcovb);
    float* wlastf = (float*)(wsb + oWlast);
    u16* xbfc   = (u16*)(wsb + oXbf);
    u16* gic    = (u16*)(wsb + oGi);
    u16* o0c    = (u16*)(wsb + oO0);
    u16* o1c    = (u16*)(wsb + oO1);

    zero_ctr_kernel<<<1, 256, 0, stream>>>(ctr);
    cvt_pad_kernel<<<288, 256, 0, stream>>>(Wih0, wih0b, G3H, 129, XPK);
    cvt_pad_kernel<<<768, 256, 0, stream>>>(Wih1, wih1b, G3H, 512, 512);
    cvt_pad_kernel<<<768, 256, 0, stream>>>(Whh0, whh0b, G3H, 512, 512);
    cvt_pad_kernel<<<768, 256, 0, stream>>>(Whh1, whh1b, G3H, 512, 512);
    cvt_pad_kernel<<<256, 256, 0, stream>>>(h0, h0bf, 512, 512, 512);
    cvt_wcov_kernel<<<64, 256, 0, stream>>>(Wcov, wcovb, wlastf);

    unsigned base = 0;
    for (int t0 = 0; t0 < T_DIM; t0 += TC) {
        int n = TC * 256 * XPK;
        int pg = (n + 255) / 256; if (pg > 2048) pg = 2048;
        cvt_pad_kernel<<<pg, 256, 0, stream>>>(
            x + (size_t)t0 * 256 * 129, xbfc, TC * 256, 129, XPK);
        gemm_bias_kernel<<<dim3(12, TC * 2), 256, 0, stream>>>(
            xbfc, XPK, wih0b, XPK, bih0, gic, G3H, XPK);
        scan_gru_kernel<<<dim3(32, 16), 256, 0, stream>>>(
            gic, whh0b, bhh0, lens, h0, h0bf, o0c, hbf0, hl0,
            ctr, t0, TC, base);
        gemm_bias_kernel<<<dim3(12, TC * 2), 256, 0, stream>>>(
            o0c, H_DIM, wih1b, H_DIM, bih1, gic, G3H, H_DIM);
        scan_gru_kernel<<<dim3(32, 16), 256, 0, stream>>>(
            gic, whh1b, bhh1, lens, h0 + (size_t)BT, h0bf + (size_t)BT,
            o1c, hbf1, hl1, ctr + 1024, t0, TC, base);
        preds_kernel<<<dim3((TC + 63) / 64, 256), 256, 0, stream>>>(
            o1c, wcovb, wlastf, bcov, x, lens, out, t0, TC);
        base += (unsigned)(TC - 1) * 32u;
    }
    dist_kernel<<<8, 256, 0, stream>>>(hl0, hl1, Wpar, bpar, out);
}